// Round 14
// baseline (400.180 us; speedup 1.0000x reference)
//
#include <hip/hip_runtime.h>
#include <hip/hip_bf16.h>
#include <math.h>

#define NB 4
#define NS 2048
#define ND 1024
#define NH 16

typedef __attribute__((ext_vector_type(8))) __bf16 bf16x8;
typedef __attribute__((ext_vector_type(4))) float f32x4;
typedef __attribute__((ext_vector_type(8))) unsigned short ushort8_t;

#define VMCNT0() asm volatile("s_waitcnt vmcnt(0)" ::: "memory")
#define VMCNT2() asm volatile("s_waitcnt vmcnt(2)" ::: "memory")
#define VMCNT4() asm volatile("s_waitcnt vmcnt(4)" ::: "memory")
#define LGKM0()  asm volatile("s_waitcnt lgkmcnt(0)" ::: "memory")
#define BAR()    __builtin_amdgcn_s_barrier()

__device__ __forceinline__ unsigned short f2bf(float f){
  union { float f; unsigned int u; } v; v.f = f;
  unsigned int r = (v.u + 0x7FFFu + ((v.u >> 16) & 1u)) >> 16;
  return (unsigned short)r;
}
__device__ __forceinline__ float bf2f(unsigned short u){
  union { unsigned int i; float f; } v; v.i = ((unsigned int)u) << 16;
  return v.f;
}
__device__ __forceinline__ f32x4 mfma16(bf16x8 a, bf16x8 b, f32x4 c){
  return __builtin_amdgcn_mfma_f32_16x16x32_bf16(a, b, c, 0, 0, 0);
}
__device__ __forceinline__ bf16x8 lds_frag(const unsigned short* p){
  ushort8_t u = *reinterpret_cast<const ushort8_t*>(p);
  return __builtin_bit_cast(bf16x8, u);
}
__device__ __forceinline__ void gl16(const unsigned short* g, unsigned short* l){
  __builtin_amdgcn_global_load_lds(
      (const __attribute__((address_space(1))) void*)g,
      (__attribute__((address_space(3))) void*)l, 16, 0, 0);
}

// ------------- fp32 -> bf16 convert, 3 tensors in one launch -------------
__global__ __launch_bounds__(256)
void k_convert3(const float* __restrict__ a, const float* __restrict__ b,
                const float* __restrict__ c, unsigned short* __restrict__ oa,
                unsigned short* __restrict__ ob, unsigned short* __restrict__ oc,
                int n4){
  int i = blockIdx.x * 256 + threadIdx.x;
  if (i >= n4) return;
  float4 v;
  if (blockIdx.y == 0){
    v = reinterpret_cast<const float4*>(a)[i];        // Q: re-read later (resid)
  } else {
    const float* in = (blockIdx.y == 1) ? b : c;      // K,V: read exactly once
    f32x4 t = __builtin_nontemporal_load(reinterpret_cast<const f32x4*>(in) + i);
    v.x = t[0]; v.y = t[1]; v.z = t[2]; v.w = t[3];
  }
  unsigned short* out = (blockIdx.y == 0) ? oa : (blockIdx.y == 1) ? ob : oc;
  ushort4 o;
  o.x = f2bf(v.x); o.y = f2bf(v.y); o.z = f2bf(v.z); o.w = f2bf(v.w);
  reinterpret_cast<ushort4*>(out)[i] = o;
}

// ------- fp32 (1024x1024) -> bf16 transposed, 4 weights in one launch -------
__global__ __launch_bounds__(256)
void k_transpose4(const float* __restrict__ w0, const float* __restrict__ w1,
                  const float* __restrict__ w2, const float* __restrict__ w3,
                  unsigned short* __restrict__ out){
  __shared__ float t[32][33];
  const float* in = (blockIdx.z == 0) ? w0 : (blockIdx.z == 1) ? w1 :
                    (blockIdx.z == 2) ? w2 : w3;
  unsigned short* o = out + (size_t)blockIdx.z * 1048576;
  const int k0 = blockIdx.x * 32, n0 = blockIdx.y * 32;
  const int tx = threadIdx.x & 31, ty = threadIdx.x >> 5;
  for (int r = ty; r < 32; r += 8)
    t[r][tx] = in[(size_t)(k0 + r) * 1024 + n0 + tx];
  __syncthreads();
  for (int r = ty; r < 32; r += 8)
    o[(size_t)(n0 + r) * 1024 + k0 + tx] = f2bf(t[tx][r]);
}

// ----- merged QKV GEMM: grid (64, 24); bn>>3 selects {Q,K,V} problem -----
__global__ __launch_bounds__(256)
void k_gemm_qkv(const unsigned short* __restrict__ A0,
                const unsigned short* __restrict__ A1,
                const unsigned short* __restrict__ A2,
                const unsigned short* __restrict__ WT,
                const float* __restrict__ b0, const float* __restrict__ b1,
                const float* __restrict__ b2,
                unsigned short* __restrict__ o0,
                unsigned short* __restrict__ o1,
                unsigned short* __restrict__ o2)
{
  constexpr int K = 1024;
  __shared__ unsigned short a_s[128 * 64];
  __shared__ unsigned short b_s[128 * 64];
  const int bm = blockIdx.x;
  const int gid = blockIdx.y >> 3, bn = blockIdx.y & 7;
  const unsigned short* A = (gid == 0) ? A0 : (gid == 1) ? A1 : A2;
  const unsigned short* BT = WT + (size_t)gid * 1048576;
  const float* bias = (gid == 0) ? b0 : (gid == 1) ? b1 : b2;
  unsigned short* outp = (gid == 0) ? o0 : (gid == 1) ? o1 : o2;

  const int tid = threadIdx.x, lane = tid & 63, w = tid >> 6;
  const int wr = w >> 1, wc = w & 1;
  const int l15 = lane & 15, l4 = lane >> 4;
  const int xsw = (l15 & 7) << 3;
  const int lr = lane >> 3;
  const int scol = ((lane & 7) << 3) ^ (lr << 3);

  const f32x4 z4 = {0.f, 0.f, 0.f, 0.f};
  f32x4 acc[4][4];
  #pragma unroll
  for (int i = 0; i < 4; ++i)
    #pragma unroll
    for (int j = 0; j < 4; ++j) acc[i][j] = z4;

  const size_t abase = (size_t)(bm * 128) * K;
  const size_t bbase = (size_t)(bn * 128) * K;

  for (int kt = 0; kt < 16; ++kt){
    __syncthreads();
    #pragma unroll
    for (int i = 0; i < 4; ++i){
      const int row = w * 32 + i * 8 + lr;
      gl16(&A[abase + (size_t)row * K + kt * 64 + scol], &a_s[(w * 32 + i * 8) * 64]);
      gl16(&BT[bbase + (size_t)row * K + kt * 64 + scol], &b_s[(w * 32 + i * 8) * 64]);
    }
    __syncthreads();
    #pragma unroll
    for (int ks = 0; ks < 2; ++ks){
      const int cb = (ks * 32 + l4 * 8) ^ xsw;
      bf16x8 af[4], bfr[4];
      #pragma unroll
      for (int mf = 0; mf < 4; ++mf)
        af[mf] = lds_frag(&a_s[(wr * 64 + mf * 16 + l15) * 64 + cb]);
      #pragma unroll
      for (int nf = 0; nf < 4; ++nf)
        bfr[nf] = lds_frag(&b_s[(wc * 64 + nf * 16 + l15) * 64 + cb]);
      #pragma unroll
      for (int mf = 0; mf < 4; ++mf)
        #pragma unroll
        for (int nf = 0; nf < 4; ++nf)
          acc[mf][nf] = mfma16(af[mf], bfr[nf], acc[mf][nf]);
    }
  }

  #pragma unroll
  for (int mf = 0; mf < 4; ++mf){
    #pragma unroll
    for (int nf = 0; nf < 4; ++nf){
      const int n = bn * 128 + wc * 64 + nf * 16 + l15;
      const float bv = bias[n];
      #pragma unroll
      for (int r = 0; r < 4; ++r){
        const int m = bm * 128 + wr * 64 + mf * 16 + l4 * 4 + r;
        const float v = acc[mf][nf][r] + bv;
        const int b = m >> 11, s = m & 2047, h = n >> 6, d = n & 63;
        if (gid <= 1)
          outp[((((size_t)b * NH + h) * NS + s) << 6) + d] = f2bf(v);
        else
          outp[(((size_t)b * NH + h) * 64 + d) * NS + s] = f2bf(v);
      }
    }
  }
}

// ------- out-projection GEMM + bias + residual -> bf16 x (for LN) -------
__global__ __launch_bounds__(256)
void k_gemm_o(const unsigned short* __restrict__ A,
              const unsigned short* __restrict__ BT,
              const float* __restrict__ bias,
              const float* __restrict__ resid,
              unsigned short* __restrict__ outp)
{
  constexpr int K = 1024;
  __shared__ unsigned short a_s[128 * 64];
  __shared__ unsigned short b_s[128 * 64];
  const int bm = blockIdx.x, bn = blockIdx.y;
  const int tid = threadIdx.x, lane = tid & 63, w = tid >> 6;
  const int wr = w >> 1, wc = w & 1;
  const int l15 = lane & 15, l4 = lane >> 4;
  const int xsw = (l15 & 7) << 3;
  const int lr = lane >> 3;
  const int scol = ((lane & 7) << 3) ^ (lr << 3);

  const f32x4 z4 = {0.f, 0.f, 0.f, 0.f};
  f32x4 acc[4][4];
  #pragma unroll
  for (int i = 0; i < 4; ++i)
    #pragma unroll
    for (int j = 0; j < 4; ++j) acc[i][j] = z4;

  const size_t abase = (size_t)(bm * 128) * K;
  const size_t bbase = (size_t)(bn * 128) * K;

  for (int kt = 0; kt < 16; ++kt){
    __syncthreads();
    #pragma unroll
    for (int i = 0; i < 4; ++i){
      const int row = w * 32 + i * 8 + lr;
      gl16(&A[abase + (size_t)row * K + kt * 64 + scol], &a_s[(w * 32 + i * 8) * 64]);
      gl16(&BT[bbase + (size_t)row * K + kt * 64 + scol], &b_s[(w * 32 + i * 8) * 64]);
    }
    __syncthreads();
    #pragma unroll
    for (int ks = 0; ks < 2; ++ks){
      const int cb = (ks * 32 + l4 * 8) ^ xsw;
      bf16x8 af[4], bfr[4];
      #pragma unroll
      for (int mf = 0; mf < 4; ++mf)
        af[mf] = lds_frag(&a_s[(wr * 64 + mf * 16 + l15) * 64 + cb]);
      #pragma unroll
      for (int nf = 0; nf < 4; ++nf)
        bfr[nf] = lds_frag(&b_s[(wc * 64 + nf * 16 + l15) * 64 + cb]);
      #pragma unroll
      for (int mf = 0; mf < 4; ++mf)
        #pragma unroll
        for (int nf = 0; nf < 4; ++nf)
          acc[mf][nf] = mfma16(af[mf], bfr[nf], acc[mf][nf]);
    }
  }

  #pragma unroll
  for (int mf = 0; mf < 4; ++mf){
    #pragma unroll
    for (int nf = 0; nf < 4; ++nf){
      const int n = bn * 128 + wc * 64 + nf * 16 + l15;
      const float bv = bias[n];
      #pragma unroll
      for (int r = 0; r < 4; ++r){
        const int m = bm * 128 + wr * 64 + mf * 16 + l4 * 4 + r;
        const size_t idx = (size_t)m * ND + n;
        outp[idx] = f2bf(acc[mf][nf][r] + bv + resid[idx]);
      }
    }
  }
}

// --- fused causal attention: R13 structure + 32KB LDS (5 blocks/CU) ---
// grid (32, 64) remapped XCD-aware; 4 waves, wave w owns 16 q-rows.
// p_s is XOR-swizzled [64*64] instead of padded [64][72].
__global__ __launch_bounds__(256, 5)
void k_attn(const unsigned short* __restrict__ qh,
            const unsigned short* __restrict__ kh,
            const unsigned short* __restrict__ vt,
            unsigned short* __restrict__ ctx,
            float* __restrict__ attn)
{
  __shared__ unsigned short k_s0[64 * 64];
  __shared__ unsigned short k_s1[64 * 64];
  __shared__ unsigned short kv2[64 * 64];   // pass1: 3rd K buffer; pass2: V tile
  __shared__ unsigned short p_s[64 * 64];   // P tile, XOR-swizzled

  const int id = blockIdx.x + 32 * blockIdx.y;
  const int swz = (id & 7) * 256 + (id >> 3);
  const int bh = swz >> 5;
  const int qb = 31 - (swz & 31);
  const int q0 = qb * 64;
  const int tid = threadIdx.x, lane = tid & 63, w = tid >> 6;
  const int l15 = lane & 15, l4 = lane >> 4;
  const int xsw = (l15 & 7) << 3;
  const int lr = lane >> 3;
  const int scol = ((lane & 7) << 3) ^ (lr << 3);
  const f32x4 z4 = {0.f, 0.f, 0.f, 0.f};
  const size_t kvb = (size_t)bh * NS * 64;

  bf16x8 qf[2];
  {
    const unsigned short* qp = &qh[kvb + (size_t)(q0 + w * 16 + l15) * 64];
    qf[0] = lds_frag(qp + l4 * 8);
    qf[1] = lds_frag(qp + 32 + l4 * 8);
  }

  const float SC = 0.125f * 1.44269504088896341f;
  const int ncomp = qb + 1;
  const int growb = q0 + w * 16 + l4 * 4;

  // ---- pass 1: row-sums (m = 0), K TRIPLE-buffered, counted vmcnt ----
  float lp[4] = {0.f, 0.f, 0.f, 0.f};

  #pragma unroll
  for (int i = 0; i < 2; ++i)
    gl16(&kh[kvb + (size_t)(w * 16 + i * 8 + lr) * 64 + scol],
         &k_s0[(w * 16 + i * 8) * 64]);
  if (ncomp > 1){
    #pragma unroll
    for (int i = 0; i < 2; ++i)
      gl16(&kh[kvb + (size_t)(64 + w * 16 + i * 8 + lr) * 64 + scol],
           &k_s1[(w * 16 + i * 8) * 64]);
    VMCNT2();
  } else {
    VMCNT0();
  }
  BAR();

  int cbi = 0;
  for (int kt = 0; kt < ncomp; ++kt){
    const bool haveNext = (kt + 1 < ncomp);
    const bool havePre  = (kt + 2 < ncomp);
    if (havePre){
      int nbi = cbi + 2; if (nbi >= 3) nbi -= 3;
      unsigned short* nb = (nbi == 0) ? k_s0 : ((nbi == 1) ? k_s1 : kv2);
      #pragma unroll
      for (int i = 0; i < 2; ++i)
        gl16(&kh[kvb + (size_t)((kt + 2) * 64 + w * 16 + i * 8 + lr) * 64 + scol],
             &nb[(w * 16 + i * 8) * 64]);
    }
    const unsigned short* cb_ = (cbi == 0) ? k_s0 : ((cbi == 1) ? k_s1 : kv2);
    f32x4 sc4[4];
    #pragma unroll
    for (int cf = 0; cf < 4; ++cf) sc4[cf] = z4;
    __builtin_amdgcn_s_setprio(1);
    #pragma unroll
    for (int ks = 0; ks < 2; ++ks){
      const int cb = (ks * 32 + l4 * 8) ^ xsw;
      #pragma unroll
      for (int cf = 0; cf < 4; ++cf){
        const bf16x8 bk = lds_frag(&cb_[(cf * 16 + l15) * 64 + cb]);
        sc4[cf] = mfma16(qf[ks], bk, sc4[cf]);
      }
    }
    __builtin_amdgcn_s_setprio(0);
    if (kt == ncomp - 1){
      #pragma unroll
      for (int cf = 0; cf < 4; ++cf){
        const int gcol = kt * 64 + cf * 16 + l15;
        #pragma unroll
        for (int r = 0; r < 4; ++r)
          lp[r] += (gcol <= growb + r) ? exp2f(sc4[cf][r] * SC) : 0.f;
      }
    } else {
      #pragma unroll
      for (int cf = 0; cf < 4; ++cf)
        #pragma unroll
        for (int r = 0; r < 4; ++r)
          lp[r] += exp2f(sc4[cf][r] * SC);
    }
    if (havePre){ VMCNT2(); } else if (haveNext){ VMCNT0(); }
    LGKM0();
    BAR();
    cbi = (cbi == 2) ? 0 : cbi + 1;
  }

  float rl[4];
  #pragma unroll
  for (int r = 0; r < 4; ++r){
    float t = lp[r];
    t += __shfl_xor(t, 1);
    t += __shfl_xor(t, 2);
    t += __shfl_xor(t, 4);
    t += __shfl_xor(t, 8);
    rl[r] = 1.f / t;
  }

  // ---- pass 2: counted-vmcnt pipeline ----
  f32x4 oacc[4];
  #pragma unroll
  for (int nf = 0; nf < 4; ++nf) oacc[nf] = z4;
  float* arow = attn + (size_t)bh * NS * NS;

  #pragma unroll
  for (int i = 0; i < 2; ++i)
    gl16(&kh[kvb + (size_t)(w * 16 + i * 8 + lr) * 64 + scol],
         &k_s0[(w * 16 + i * 8) * 64]);
  VMCNT0();
  BAR();
  int cur = 0;

  for (int kt = 0; kt < ncomp; ++kt){
    const bool haveK = (kt + 1 < ncomp);
    unsigned short* kcur = cur ? k_s1 : k_s0;
    unsigned short* knxt = cur ? k_s0 : k_s1;
    #pragma unroll
    for (int i = 0; i < 2; ++i){
      const int row = w * 16 + i * 8 + lr;
      gl16(&vt[kvb + (size_t)row * NS + kt * 64 + scol], &kv2[(w * 16 + i * 8) * 64]);
    }
    if (haveK){
      #pragma unroll
      for (int i = 0; i < 2; ++i)
        gl16(&kh[kvb + (size_t)((kt + 1) * 64 + w * 16 + i * 8 + lr) * 64 + scol],
             &knxt[(w * 16 + i * 8) * 64]);
    }
    f32x4 sc4[4];
    #pragma unroll
    for (int cf = 0; cf < 4; ++cf) sc4[cf] = z4;
    __builtin_amdgcn_s_setprio(1);
    #pragma unroll
    for (int ks = 0; ks < 2; ++ks){
      const int cb = (ks * 32 + l4 * 8) ^ xsw;
      #pragma unroll
      for (int cf = 0; cf < 4; ++cf){
        const bf16x8 bk = lds_frag(&kcur[(cf * 16 + l15) * 64 + cb]);
        sc4[cf] = mfma16(qf[ks], bk, sc4[cf]);
      }
    }
    __builtin_amdgcn_s_setprio(0);
    if (kt == ncomp - 1){
      #pragma unroll
      for (int cf = 0; cf < 4; ++cf){
        const int gcol = kt * 64 + cf * 16 + l15;
        #pragma unroll
        for (int r = 0; r < 4; ++r){
          const float a = (gcol <= growb + r) ? exp2f(sc4[cf][r] * SC) * rl[r] : 0.f;
          const int row = w * 16 + l4 * 4 + r;
          p_s[row * 64 + ((cf * 16 + l15) ^ ((row & 7) << 3))] = f2bf(a);
        }
      }
    } else {
      #pragma unroll
      for (int cf = 0; cf < 4; ++cf)
        #pragma unroll
        for (int r = 0; r < 4; ++r){
          const float a = exp2f(sc4[cf][r] * SC) * rl[r];
          const int row = w * 16 + l4 * 4 + r;
          p_s[row * 64 + ((cf * 16 + l15) ^ ((row & 7) << 3))] = f2bf(a);
        }
    }
    if (haveK){ VMCNT2(); } else { VMCNT0(); }
    LGKM0();
    BAR();
    // coalesced attn stores, nontemporal (streaming, never re-read)
    #pragma unroll
    for (int it = 0; it < 4; ++it){
      const int row = it * 16 + (tid >> 4);
      const int c0 = (tid & 15) * 4;
      const ushort4 u = *reinterpret_cast<const ushort4*>(
          &p_s[row * 64 + (c0 ^ ((row & 7) << 3))]);
      f32x4 f4;
      f4[0] = bf2f(u.x); f4[1] = bf2f(u.y); f4[2] = bf2f(u.z); f4[3] = bf2f(u.w);
      __builtin_nontemporal_store(
          f4, reinterpret_cast<f32x4*>(&arow[(size_t)(q0 + row) * NS + kt * 64 + c0]));
    }
    __builtin_amdgcn_s_setprio(1);
    #pragma unroll
    for (int ks2 = 0; ks2 < 2; ++ks2){
      const int prow = w * 16 + l15;
      const bf16x8 ap = lds_frag(
          &p_s[prow * 64 + ((ks2 * 32 + l4 * 8) ^ ((prow & 7) << 3))]);
      const int cb = (ks2 * 32 + l4 * 8) ^ xsw;
      #pragma unroll
      for (int nf = 0; nf < 4; ++nf){
        const bf16x8 bv = lds_frag(&kv2[(nf * 16 + l15) * 64 + cb]);
        oacc[nf] = mfma16(ap, bv, oacc[nf]);
      }
    }
    __builtin_amdgcn_s_setprio(0);
    if (haveK){
      VMCNT4();
      BAR();
    }
    cur ^= 1;
  }

  const int b = bh >> 4, h = bh & 15;
  #pragma unroll
  for (int nf = 0; nf < 4; ++nf){
    #pragma unroll
    for (int r = 0; r < 4; ++r){
      const int s = growb + r;
      ctx[((size_t)b * NS + s) * ND + h * 64 + nf * 16 + l15] = f2bf(oacc[nf][r]);
    }
  }

  // zero-fill masked upper region of attn (cols >= q0+64), nontemporal
  const int zc0 = ncomp * 64;
  if (zc0 < NS){
    const f32x4 zz = {0.f, 0.f, 0.f, 0.f};
    for (int r = 0; r < 64; ++r){
      float* rp = arow + (size_t)(q0 + r) * NS;
      for (int c = zc0 + tid * 4; c < NS; c += 1024)
        __builtin_nontemporal_store(zz, reinterpret_cast<f32x4*>(rp + c));
    }
  }
}

// ---------------- LayerNorm over D=1024 (bf16 in, fp32 out) ----------------
__global__ __launch_bounds__(256)
void k_ln(const unsigned short* __restrict__ x, const float* __restrict__ gamma,
          const float* __restrict__ beta, float* __restrict__ y){
  const int row = blockIdx.x;
  const ushort4 u = reinterpret_cast<const ushort4*>(x + (size_t)row * ND)[threadIdx.x];
  float v0 = bf2f(u.x), v1 = bf2f(u.y), v2 = bf2f(u.z), v3 = bf2f(u.w);
  float s = v0 + v1 + v2 + v3;
  float ss = v0 * v0 + v1 * v1 + v2 * v2 + v3 * v3;
  #pragma unroll
  for (int off = 32; off; off >>= 1){
    s += __shfl_xor(s, off);
    ss += __shfl_xor(ss, off);
  }
  __shared__ float rs[4], rss[4];
  const int w = threadIdx.x >> 6;
  if ((threadIdx.x & 63) == 0){ rs[w] = s; rss[w] = ss; }
  __syncthreads();
  s = rs[0] + rs[1] + rs[2] + rs[3];
  ss = rss[0] + rss[1] + rss[2] + rss[3];
  const float mu = s * (1.f / ND);
  const float var = ss * (1.f / ND) - mu * mu;
  const float rstd = rsqrtf(var + 1e-5f);
  const float4 g = reinterpret_cast<const float4*>(gamma)[threadIdx.x];
  const float4 be = reinterpret_cast<const float4*>(beta)[threadIdx.x];
  f32x4 o;
  o[0] = (v0 - mu) * rstd * g.x + be.x;
  o[1] = (v1 - mu) * rstd * g.y + be.y;
  o[2] = (v2 - mu) * rstd * g.z + be.z;
  o[3] = (v3 - mu) * rstd * g.w + be.w;
  __builtin_nontemporal_store(
      o, reinterpret_cast<f32x4*>(y + (size_t)row * ND) + threadIdx.x);
}

extern "C" void kernel_launch(void* const* d_in, const int* in_sizes, int n_in,
                              void* d_out, int out_size, void* d_ws, size_t ws_size,
                              hipStream_t stream){
  const float* Q   = (const float*)d_in[0];
  const float* Kin = (const float*)d_in[1];
  const float* V   = (const float*)d_in[2];
  const float* W_Q = (const float*)d_in[4];
  const float* b_Q = (const float*)d_in[5];
  const float* W_K = (const float*)d_in[6];
  const float* b_K = (const float*)d_in[7];
  const float* W_V = (const float*)d_in[8];
  const float* b_V = (const float*)d_in[9];
  const float* W_O = (const float*)d_in[10];
  const float* b_O = (const float*)d_in[11];
  const float* g   = (const float*)d_in[12];
  const float* be  = (const float*)d_in[13];

  char* ws = (char*)d_ws;
  const size_t SZ = (size_t)8192 * 1024 * 2;
  unsigned short* Qb = (unsigned short*)(ws);
  unsigned short* Kb = (unsigned short*)(ws + SZ);
  unsigned short* Vb = (unsigned short*)(ws + 2 * SZ);
  unsigned short* WT = (unsigned short*)(ws + 3 * SZ);
  unsigned short* qh = (unsigned short*)(ws + 3 * SZ + 4 * 2097152);
  unsigned short* kh = qh + (size_t)8388608;
  unsigned short* vt = kh + (size_t)8388608;
  unsigned short* ctx = Qb;                    // alias: Qb dead after q-proj
  unsigned short* x = Kb;                      // alias: Kb dead after k-proj
  float* y = (float*)d_out;
  float* attn = y + (size_t)NB * NS * ND;

  const int n4 = (NB * NS * ND) / 4;
  k_convert3<<<dim3(n4 / 256, 3), 256, 0, stream>>>(Q, Kin, V, Qb, Kb, Vb, n4);
  k_transpose4<<<dim3(32, 32, 4), 256, 0, stream>>>(W_Q, W_K, W_V, W_O, WT);

  k_gemm_qkv<<<dim3(64, 24), 256, 0, stream>>>(Qb, Kb, Vb, WT, b_Q, b_K, b_V,
                                               qh, kh, vt);

  k_attn<<<dim3(32, 64), 256, 0, stream>>>(qh, kh, vt, ctx, attn);

  k_gemm_o<<<dim3(64, 8), 256, 0, stream>>>(ctx, WT + 3 * 1048576, b_O, Q, x);

  k_ln<<<NB * NS, 256, 0, stream>>>(x, g, be, y);
}

// Round 15
// 388.974 us; speedup vs baseline: 1.0288x; 1.0288x over previous
//
#include <hip/hip_runtime.h>
#include <hip/hip_bf16.h>
#include <math.h>

#define NB 4
#define NS 2048
#define ND 1024
#define NH 16

typedef __attribute__((ext_vector_type(8))) __bf16 bf16x8;
typedef __attribute__((ext_vector_type(4))) float f32x4;
typedef __attribute__((ext_vector_type(8))) unsigned short ushort8_t;

#define VMCNT0() asm volatile("s_waitcnt vmcnt(0)" ::: "memory")
#define VMCNT2() asm volatile("s_waitcnt vmcnt(2)" ::: "memory")
#define VMCNT4() asm volatile("s_waitcnt vmcnt(4)" ::: "memory")
#define LGKM0()  asm volatile("s_waitcnt lgkmcnt(0)" ::: "memory")
#define BAR()    __builtin_amdgcn_s_barrier()

__device__ __forceinline__ unsigned short f2bf(float f){
  union { float f; unsigned int u; } v; v.f = f;
  unsigned int r = (v.u + 0x7FFFu + ((v.u >> 16) & 1u)) >> 16;
  return (unsigned short)r;
}
__device__ __forceinline__ float bf2f(unsigned short u){
  union { unsigned int i; float f; } v; v.i = ((unsigned int)u) << 16;
  return v.f;
}
__device__ __forceinline__ f32x4 mfma16(bf16x8 a, bf16x8 b, f32x4 c){
  return __builtin_amdgcn_mfma_f32_16x16x32_bf16(a, b, c, 0, 0, 0);
}
__device__ __forceinline__ bf16x8 lds_frag(const unsigned short* p){
  ushort8_t u = *reinterpret_cast<const ushort8_t*>(p);
  return __builtin_bit_cast(bf16x8, u);
}
__device__ __forceinline__ void gl16(const unsigned short* g, unsigned short* l){
  __builtin_amdgcn_global_load_lds(
      (const __attribute__((address_space(1))) void*)g,
      (__attribute__((address_space(3))) void*)l, 16, 0, 0);
}

// ------------- fp32 -> bf16 convert, 3 tensors in one launch -------------
__global__ __launch_bounds__(256)
void k_convert3(const float* __restrict__ a, const float* __restrict__ b,
                const float* __restrict__ c, unsigned short* __restrict__ oa,
                unsigned short* __restrict__ ob, unsigned short* __restrict__ oc,
                int n4){
  int i = blockIdx.x * 256 + threadIdx.x;
  if (i >= n4) return;
  const float* in = (blockIdx.y == 0) ? a : (blockIdx.y == 1) ? b : c;
  unsigned short* out = (blockIdx.y == 0) ? oa : (blockIdx.y == 1) ? ob : oc;
  float4 v = reinterpret_cast<const float4*>(in)[i];
  ushort4 o;
  o.x = f2bf(v.x); o.y = f2bf(v.y); o.z = f2bf(v.z); o.w = f2bf(v.w);
  reinterpret_cast<ushort4*>(out)[i] = o;
}

// ------- fp32 (1024x1024) -> bf16 transposed, 4 weights in one launch -------
__global__ __launch_bounds__(256)
void k_transpose4(const float* __restrict__ w0, const float* __restrict__ w1,
                  const float* __restrict__ w2, const float* __restrict__ w3,
                  unsigned short* __restrict__ out){
  __shared__ float t[32][33];
  const float* in = (blockIdx.z == 0) ? w0 : (blockIdx.z == 1) ? w1 :
                    (blockIdx.z == 2) ? w2 : w3;
  unsigned short* o = out + (size_t)blockIdx.z * 1048576;
  const int k0 = blockIdx.x * 32, n0 = blockIdx.y * 32;
  const int tx = threadIdx.x & 31, ty = threadIdx.x >> 5;
  for (int r = ty; r < 32; r += 8)
    t[r][tx] = in[(size_t)(k0 + r) * 1024 + n0 + tx];
  __syncthreads();
  for (int r = ty; r < 32; r += 8)
    o[(size_t)(n0 + r) * 1024 + k0 + tx] = f2bf(t[tx][r]);
}

// ----- merged QKV GEMM: grid (64, 24); bn>>3 selects {Q,K,V} problem -----
__global__ __launch_bounds__(256)
void k_gemm_qkv(const unsigned short* __restrict__ A0,
                const unsigned short* __restrict__ A1,
                const unsigned short* __restrict__ A2,
                const unsigned short* __restrict__ WT,
                const float* __restrict__ b0, const float* __restrict__ b1,
                const float* __restrict__ b2,
                unsigned short* __restrict__ o0,
                unsigned short* __restrict__ o1,
                unsigned short* __restrict__ o2)
{
  constexpr int K = 1024;
  __shared__ unsigned short a_s[128 * 64];
  __shared__ unsigned short b_s[128 * 64];
  const int bm = blockIdx.x;
  const int gid = blockIdx.y >> 3, bn = blockIdx.y & 7;
  const unsigned short* A = (gid == 0) ? A0 : (gid == 1) ? A1 : A2;
  const unsigned short* BT = WT + (size_t)gid * 1048576;
  const float* bias = (gid == 0) ? b0 : (gid == 1) ? b1 : b2;
  unsigned short* outp = (gid == 0) ? o0 : (gid == 1) ? o1 : o2;

  const int tid = threadIdx.x, lane = tid & 63, w = tid >> 6;
  const int wr = w >> 1, wc = w & 1;
  const int l15 = lane & 15, l4 = lane >> 4;
  const int xsw = (l15 & 7) << 3;
  const int lr = lane >> 3;
  const int scol = ((lane & 7) << 3) ^ (lr << 3);

  const f32x4 z4 = {0.f, 0.f, 0.f, 0.f};
  f32x4 acc[4][4];
  #pragma unroll
  for (int i = 0; i < 4; ++i)
    #pragma unroll
    for (int j = 0; j < 4; ++j) acc[i][j] = z4;

  const size_t abase = (size_t)(bm * 128) * K;
  const size_t bbase = (size_t)(bn * 128) * K;

  for (int kt = 0; kt < 16; ++kt){
    __syncthreads();
    #pragma unroll
    for (int i = 0; i < 4; ++i){
      const int row = w * 32 + i * 8 + lr;
      gl16(&A[abase + (size_t)row * K + kt * 64 + scol], &a_s[(w * 32 + i * 8) * 64]);
      gl16(&BT[bbase + (size_t)row * K + kt * 64 + scol], &b_s[(w * 32 + i * 8) * 64]);
    }
    __syncthreads();
    #pragma unroll
    for (int ks = 0; ks < 2; ++ks){
      const int cb = (ks * 32 + l4 * 8) ^ xsw;
      bf16x8 af[4], bfr[4];
      #pragma unroll
      for (int mf = 0; mf < 4; ++mf)
        af[mf] = lds_frag(&a_s[(wr * 64 + mf * 16 + l15) * 64 + cb]);
      #pragma unroll
      for (int nf = 0; nf < 4; ++nf)
        bfr[nf] = lds_frag(&b_s[(wc * 64 + nf * 16 + l15) * 64 + cb]);
      #pragma unroll
      for (int mf = 0; mf < 4; ++mf)
        #pragma unroll
        for (int nf = 0; nf < 4; ++nf)
          acc[mf][nf] = mfma16(af[mf], bfr[nf], acc[mf][nf]);
    }
  }

  #pragma unroll
  for (int mf = 0; mf < 4; ++mf){
    #pragma unroll
    for (int nf = 0; nf < 4; ++nf){
      const int n = bn * 128 + wc * 64 + nf * 16 + l15;
      const float bv = bias[n];
      #pragma unroll
      for (int r = 0; r < 4; ++r){
        const int m = bm * 128 + wr * 64 + mf * 16 + l4 * 4 + r;
        const float v = acc[mf][nf][r] + bv;
        const int b = m >> 11, s = m & 2047, h = n >> 6, d = n & 63;
        if (gid <= 1)
          outp[((((size_t)b * NH + h) * NS + s) << 6) + d] = f2bf(v);
        else
          outp[(((size_t)b * NH + h) * 64 + d) * NS + s] = f2bf(v);
      }
    }
  }
}

// ------- out-projection GEMM + bias + residual -> bf16 x (for LN) -------
__global__ __launch_bounds__(256)
void k_gemm_o(const unsigned short* __restrict__ A,
              const unsigned short* __restrict__ BT,
              const float* __restrict__ bias,
              const float* __restrict__ resid,
              unsigned short* __restrict__ outp)
{
  constexpr int K = 1024;
  __shared__ unsigned short a_s[128 * 64];
  __shared__ unsigned short b_s[128 * 64];
  const int bm = blockIdx.x, bn = blockIdx.y;
  const int tid = threadIdx.x, lane = tid & 63, w = tid >> 6;
  const int wr = w >> 1, wc = w & 1;
  const int l15 = lane & 15, l4 = lane >> 4;
  const int xsw = (l15 & 7) << 3;
  const int lr = lane >> 3;
  const int scol = ((lane & 7) << 3) ^ (lr << 3);

  const f32x4 z4 = {0.f, 0.f, 0.f, 0.f};
  f32x4 acc[4][4];
  #pragma unroll
  for (int i = 0; i < 4; ++i)
    #pragma unroll
    for (int j = 0; j < 4; ++j) acc[i][j] = z4;

  const size_t abase = (size_t)(bm * 128) * K;
  const size_t bbase = (size_t)(bn * 128) * K;

  for (int kt = 0; kt < 16; ++kt){
    __syncthreads();
    #pragma unroll
    for (int i = 0; i < 4; ++i){
      const int row = w * 32 + i * 8 + lr;
      gl16(&A[abase + (size_t)row * K + kt * 64 + scol], &a_s[(w * 32 + i * 8) * 64]);
      gl16(&BT[bbase + (size_t)row * K + kt * 64 + scol], &b_s[(w * 32 + i * 8) * 64]);
    }
    __syncthreads();
    #pragma unroll
    for (int ks = 0; ks < 2; ++ks){
      const int cb = (ks * 32 + l4 * 8) ^ xsw;
      bf16x8 af[4], bfr[4];
      #pragma unroll
      for (int mf = 0; mf < 4; ++mf)
        af[mf] = lds_frag(&a_s[(wr * 64 + mf * 16 + l15) * 64 + cb]);
      #pragma unroll
      for (int nf = 0; nf < 4; ++nf)
        bfr[nf] = lds_frag(&b_s[(wc * 64 + nf * 16 + l15) * 64 + cb]);
      #pragma unroll
      for (int mf = 0; mf < 4; ++mf)
        #pragma unroll
        for (int nf = 0; nf < 4; ++nf)
          acc[mf][nf] = mfma16(af[mf], bfr[nf], acc[mf][nf]);
    }
  }

  #pragma unroll
  for (int mf = 0; mf < 4; ++mf){
    #pragma unroll
    for (int nf = 0; nf < 4; ++nf){
      const int n = bn * 128 + wc * 64 + nf * 16 + l15;
      const float bv = bias[n];
      #pragma unroll
      for (int r = 0; r < 4; ++r){
        const int m = bm * 128 + wr * 64 + mf * 16 + l4 * 4 + r;
        const size_t idx = (size_t)m * ND + n;
        outp[idx] = f2bf(acc[mf][nf][r] + bv + resid[idx]);
      }
    }
  }
}

// ------- fused causal attention (R8 structure) + nontemporal attn stores -------
// grid (32, 64) remapped XCD-aware; 4 waves, wave w owns 16 q-rows.
__global__ __launch_bounds__(256, 4)
void k_attn(const unsigned short* __restrict__ qh,
            const unsigned short* __restrict__ kh,
            const unsigned short* __restrict__ vt,
            unsigned short* __restrict__ ctx,
            float* __restrict__ attn)
{
  __shared__ unsigned short k_s0[64 * 64];
  __shared__ unsigned short k_s1[64 * 64];
  __shared__ unsigned short kv2[64 * 64];   // pass1: 3rd K buffer; pass2: V tile
  __shared__ unsigned short p_s[64][72];

  const int id = blockIdx.x + 32 * blockIdx.y;
  const int swz = (id & 7) * 256 + (id >> 3);
  const int bh = swz >> 5;
  const int qb = 31 - (swz & 31);
  const int q0 = qb * 64;
  const int tid = threadIdx.x, lane = tid & 63, w = tid >> 6;
  const int l15 = lane & 15, l4 = lane >> 4;
  const int xsw = (l15 & 7) << 3;
  const int lr = lane >> 3;
  const int scol = ((lane & 7) << 3) ^ (lr << 3);
  const f32x4 z4 = {0.f, 0.f, 0.f, 0.f};
  const size_t kvb = (size_t)bh * NS * 64;

  bf16x8 qf[2];
  {
    const unsigned short* qp = &qh[kvb + (size_t)(q0 + w * 16 + l15) * 64];
    qf[0] = lds_frag(qp + l4 * 8);
    qf[1] = lds_frag(qp + 32 + l4 * 8);
  }

  const float SC = 0.125f * 1.44269504088896341f;
  const int ncomp = qb + 1;
  const int growb = q0 + w * 16 + l4 * 4;

  // ---- pass 1: row-sums (m = 0), K TRIPLE-buffered, counted vmcnt ----
  float lp[4] = {0.f, 0.f, 0.f, 0.f};

  #pragma unroll
  for (int i = 0; i < 2; ++i)
    gl16(&kh[kvb + (size_t)(w * 16 + i * 8 + lr) * 64 + scol],
         &k_s0[(w * 16 + i * 8) * 64]);
  if (ncomp > 1){
    #pragma unroll
    for (int i = 0; i < 2; ++i)
      gl16(&kh[kvb + (size_t)(64 + w * 16 + i * 8 + lr) * 64 + scol],
           &k_s1[(w * 16 + i * 8) * 64]);
    VMCNT2();
  } else {
    VMCNT0();
  }
  BAR();

  int cbi = 0;
  for (int kt = 0; kt < ncomp; ++kt){
    const bool haveNext = (kt + 1 < ncomp);
    const bool havePre  = (kt + 2 < ncomp);
    if (havePre){
      int nbi = cbi + 2; if (nbi >= 3) nbi -= 3;
      unsigned short* nb = (nbi == 0) ? k_s0 : ((nbi == 1) ? k_s1 : kv2);
      #pragma unroll
      for (int i = 0; i < 2; ++i)
        gl16(&kh[kvb + (size_t)((kt + 2) * 64 + w * 16 + i * 8 + lr) * 64 + scol],
             &nb[(w * 16 + i * 8) * 64]);
    }
    const unsigned short* cb_ = (cbi == 0) ? k_s0 : ((cbi == 1) ? k_s1 : kv2);
    f32x4 sc4[4];
    #pragma unroll
    for (int cf = 0; cf < 4; ++cf) sc4[cf] = z4;
    __builtin_amdgcn_s_setprio(1);
    #pragma unroll
    for (int ks = 0; ks < 2; ++ks){
      const int cb = (ks * 32 + l4 * 8) ^ xsw;
      #pragma unroll
      for (int cf = 0; cf < 4; ++cf){
        const bf16x8 bk = lds_frag(&cb_[(cf * 16 + l15) * 64 + cb]);
        sc4[cf] = mfma16(qf[ks], bk, sc4[cf]);
      }
    }
    __builtin_amdgcn_s_setprio(0);
    if (kt == ncomp - 1){
      #pragma unroll
      for (int cf = 0; cf < 4; ++cf){
        const int gcol = kt * 64 + cf * 16 + l15;
        #pragma unroll
        for (int r = 0; r < 4; ++r)
          lp[r] += (gcol <= growb + r) ? exp2f(sc4[cf][r] * SC) : 0.f;
      }
    } else {
      #pragma unroll
      for (int cf = 0; cf < 4; ++cf)
        #pragma unroll
        for (int r = 0; r < 4; ++r)
          lp[r] += exp2f(sc4[cf][r] * SC);
    }
    if (havePre){ VMCNT2(); } else if (haveNext){ VMCNT0(); }
    LGKM0();
    BAR();
    cbi = (cbi == 2) ? 0 : cbi + 1;
  }

  float rl[4];
  #pragma unroll
  for (int r = 0; r < 4; ++r){
    float t = lp[r];
    t += __shfl_xor(t, 1);
    t += __shfl_xor(t, 2);
    t += __shfl_xor(t, 4);
    t += __shfl_xor(t, 8);
    rl[r] = 1.f / t;
  }

  // ---- pass 2: counted-vmcnt pipeline ----
  f32x4 oacc[4];
  #pragma unroll
  for (int nf = 0; nf < 4; ++nf) oacc[nf] = z4;
  float* arow = attn + (size_t)bh * NS * NS;

  #pragma unroll
  for (int i = 0; i < 2; ++i)
    gl16(&kh[kvb + (size_t)(w * 16 + i * 8 + lr) * 64 + scol],
         &k_s0[(w * 16 + i * 8) * 64]);
  VMCNT0();
  BAR();
  int cur = 0;

  for (int kt = 0; kt < ncomp; ++kt){
    const bool haveK = (kt + 1 < ncomp);
    unsigned short* kcur = cur ? k_s1 : k_s0;
    unsigned short* knxt = cur ? k_s0 : k_s1;
    #pragma unroll
    for (int i = 0; i < 2; ++i){
      const int row = w * 16 + i * 8 + lr;
      gl16(&vt[kvb + (size_t)row * NS + kt * 64 + scol], &kv2[(w * 16 + i * 8) * 64]);
    }
    if (haveK){
      #pragma unroll
      for (int i = 0; i < 2; ++i)
        gl16(&kh[kvb + (size_t)((kt + 1) * 64 + w * 16 + i * 8 + lr) * 64 + scol],
             &knxt[(w * 16 + i * 8) * 64]);
    }
    f32x4 sc4[4];
    #pragma unroll
    for (int cf = 0; cf < 4; ++cf) sc4[cf] = z4;
    __builtin_amdgcn_s_setprio(1);
    #pragma unroll
    for (int ks = 0; ks < 2; ++ks){
      const int cb = (ks * 32 + l4 * 8) ^ xsw;
      #pragma unroll
      for (int cf = 0; cf < 4; ++cf){
        const bf16x8 bk = lds_frag(&kcur[(cf * 16 + l15) * 64 + cb]);
        sc4[cf] = mfma16(qf[ks], bk, sc4[cf]);
      }
    }
    __builtin_amdgcn_s_setprio(0);
    if (kt == ncomp - 1){
      #pragma unroll
      for (int cf = 0; cf < 4; ++cf){
        const int gcol = kt * 64 + cf * 16 + l15;
        #pragma unroll
        for (int r = 0; r < 4; ++r){
          const float a = (gcol <= growb + r) ? exp2f(sc4[cf][r] * SC) * rl[r] : 0.f;
          p_s[w * 16 + l4 * 4 + r][cf * 16 + l15] = f2bf(a);
        }
      }
    } else {
      #pragma unroll
      for (int cf = 0; cf < 4; ++cf)
        #pragma unroll
        for (int r = 0; r < 4; ++r)
          p_s[w * 16 + l4 * 4 + r][cf * 16 + l15] = f2bf(exp2f(sc4[cf][r] * SC) * rl[r]);
    }
    if (haveK){ VMCNT2(); } else { VMCNT0(); }
    LGKM0();
    BAR();
    // coalesced attn stores, nontemporal (streaming, never re-read)
    #pragma unroll
    for (int it = 0; it < 4; ++it){
      const int row = it * 16 + (tid >> 4);
      const int c0 = (tid & 15) * 4;
      const ushort4 u = *reinterpret_cast<const ushort4*>(&p_s[row][c0]);
      f32x4 f4;
      f4[0] = bf2f(u.x); f4[1] = bf2f(u.y); f4[2] = bf2f(u.z); f4[3] = bf2f(u.w);
      __builtin_nontemporal_store(
          f4, reinterpret_cast<f32x4*>(&arow[(size_t)(q0 + row) * NS + kt * 64 + c0]));
    }
    __builtin_amdgcn_s_setprio(1);
    #pragma unroll
    for (int ks2 = 0; ks2 < 2; ++ks2){
      const bf16x8 ap = lds_frag(&p_s[w * 16 + l15][ks2 * 32 + l4 * 8]);
      const int cb = (ks2 * 32 + l4 * 8) ^ xsw;
      #pragma unroll
      for (int nf = 0; nf < 4; ++nf){
        const bf16x8 bv = lds_frag(&kv2[(nf * 16 + l15) * 64 + cb]);
        oacc[nf] = mfma16(ap, bv, oacc[nf]);
      }
    }
    __builtin_amdgcn_s_setprio(0);
    if (haveK){
      VMCNT4();
      BAR();
    }
    cur ^= 1;
  }

  const int b = bh >> 4, h = bh & 15;
  #pragma unroll
  for (int nf = 0; nf < 4; ++nf){
    #pragma unroll
    for (int r = 0; r < 4; ++r){
      const int s = growb + r;
      ctx[((size_t)b * NS + s) * ND + h * 64 + nf * 16 + l15] = f2bf(oacc[nf][r]);
    }
  }

  // zero-fill masked upper region of attn (cols >= q0+64), nontemporal
  const int zc0 = ncomp * 64;
  if (zc0 < NS){
    const f32x4 zz = {0.f, 0.f, 0.f, 0.f};
    for (int r = 0; r < 64; ++r){
      float* rp = arow + (size_t)(q0 + r) * NS;
      for (int c = zc0 + tid * 4; c < NS; c += 1024)
        __builtin_nontemporal_store(zz, reinterpret_cast<f32x4*>(rp + c));
    }
  }
}

// ---------------- LayerNorm over D=1024 (bf16 in, fp32 out) ----------------
__global__ __launch_bounds__(256)
void k_ln(const unsigned short* __restrict__ x, const float* __restrict__ gamma,
          const float* __restrict__ beta, float* __restrict__ y){
  const int row = blockIdx.x;
  const ushort4 u = reinterpret_cast<const ushort4*>(x + (size_t)row * ND)[threadIdx.x];
  float v0 = bf2f(u.x), v1 = bf2f(u.y), v2 = bf2f(u.z), v3 = bf2f(u.w);
  float s = v0 + v1 + v2 + v3;
  float ss = v0 * v0 + v1 * v1 + v2 * v2 + v3 * v3;
  #pragma unroll
  for (int off = 32; off; off >>= 1){
    s += __shfl_xor(s, off);
    ss += __shfl_xor(ss, off);
  }
  __shared__ float rs[4], rss[4];
  const int w = threadIdx.x >> 6;
  if ((threadIdx.x & 63) == 0){ rs[w] = s; rss[w] = ss; }
  __syncthreads();
  s = rs[0] + rs[1] + rs[2] + rs[3];
  ss = rss[0] + rss[1] + rss[2] + rss[3];
  const float mu = s * (1.f / ND);
  const float var = ss * (1.f / ND) - mu * mu;
  const float rstd = rsqrtf(var + 1e-5f);
  const float4 g = reinterpret_cast<const float4*>(gamma)[threadIdx.x];
  const float4 be = reinterpret_cast<const float4*>(beta)[threadIdx.x];
  float4 o;
  o.x = (v0 - mu) * rstd * g.x + be.x;
  o.y = (v1 - mu) * rstd * g.y + be.y;
  o.z = (v2 - mu) * rstd * g.z + be.z;
  o.w = (v3 - mu) * rstd * g.w + be.w;
  reinterpret_cast<float4*>(y + (size_t)row * ND)[threadIdx.x] = o;
}

extern "C" void kernel_launch(void* const* d_in, const int* in_sizes, int n_in,
                              void* d_out, int out_size, void* d_ws, size_t ws_size,
                              hipStream_t stream){
  const float* Q   = (const float*)d_in[0];
  const float* Kin = (const float*)d_in[1];
  const float* V   = (const float*)d_in[2];
  const float* W_Q = (const float*)d_in[4];
  const float* b_Q = (const float*)d_in[5];
  const float* W_K = (const float*)d_in[6];
  const float* b_K = (const float*)d_in[7];
  const float* W_V = (const float*)d_in[8];
  const float* b_V = (const float*)d_in[9];
  const float* W_O = (const float*)d_in[10];
  const float* b_O = (const float*)d_in[11];
  const float* g   = (const float*)d_in[12];
  const float* be  = (const float*)d_in[13];

  char* ws = (char*)d_ws;
  const size_t SZ = (size_t)8192 * 1024 * 2;
  unsigned short* Qb = (unsigned short*)(ws);
  unsigned short* Kb = (unsigned short*)(ws + SZ);
  unsigned short* Vb = (unsigned short*)(ws + 2 * SZ);
  unsigned short* WT = (unsigned short*)(ws + 3 * SZ);
  unsigned short* qh = (unsigned short*)(ws + 3 * SZ + 4 * 2097152);
  unsigned short* kh = qh + (size_t)8388608;
  unsigned short* vt = kh + (size_t)8388608;
  unsigned short* ctx = Qb;                    // alias: Qb dead after q-proj
  unsigned short* x = Kb;                      // alias: Kb dead after k-proj
  float* y = (float*)d_out;
  float* attn = y + (size_t)NB * NS * ND;

  const int n4 = (NB * NS * ND) / 4;
  k_convert3<<<dim3(n4 / 256, 3), 256, 0, stream>>>(Q, Kin, V, Qb, Kb, Vb, n4);
  k_transpose4<<<dim3(32, 32, 4), 256, 0, stream>>>(W_Q, W_K, W_V, W_O, WT);

  k_gemm_qkv<<<dim3(64, 24), 256, 0, stream>>>(Qb, Kb, Vb, WT, b_Q, b_K, b_V,
                                               qh, kh, vt);

  k_attn<<<dim3(32, 64), 256, 0, stream>>>(qh, kh, vt, ctx, attn);

  k_gemm_o<<<dim3(64, 8), 256, 0, stream>>>(ctx, WT + 3 * 1048576, b_O, Q, x);

  k_ln<<<NB * NS, 256, 0, stream>>>(x, g, be, y);
}